// Round 2
// baseline (880.096 us; speedup 1.0000x reference)
//
#include <hip/hip_runtime.h>
#include <cmath>

#define TSX 32
#define HALO 5
#define XPAD 8        // staged halo per side (multiple of 4 for float4 masking)
#define NCOLS 42      // TSX + 2*HALO (columns vertical-blurred)
#define CHROWS 26     // 16 + 2*HALO  (input rows per 16-row chunk)
#define RSTR 48       // raw row stride (floats) = TSX + 2*XPAD
#define RF4 12        // float4s per raw row
#define VSTR 44       // vb row stride (floats), multiple of 4 for b128
#define WIDTH 512
#define HEIGHT 512

struct GW { float g[11]; };

__device__ __forceinline__ float ssim_term(float mu1, float mu2,
                                           float x2b, float y2b, float xyb)
{
    const float C1 = 1e-4f, C2 = 9e-4f;
    float mu12 = mu1 * mu2;
    float num  = (2.f * mu12 + C1) * (2.f * (xyb - mu12) + C2);
    float den  = (mu1 * mu1 + mu2 * mu2 + C1) *
                 ((x2b - mu1 * mu1) + (y2b - mu2 * mu2) + C2);
    return num / den;
}

__global__ __launch_bounds__(256, 4)
void ssim_tile(const float* __restrict__ fI, const float* __restrict__ aI,
               const float* __restrict__ bI, float* __restrict__ gsum,
               GW gw, int W, int H)
{
    __shared__ __align__(16) float raw[3][CHROWS * RSTR];   // 15.0 KB
    __shared__ __align__(16) float vb[8][16 * VSTR];        // 22.5 KB
    __shared__ float red[4];

    const int tid = threadIdx.x;
    const int bx = blockIdx.x;
    const int x0 = bx * TSX;
    const int y0 = blockIdx.y * 32;
    const size_t pbase = (size_t)blockIdx.z * (size_t)(W * H);
    const bool xl = (bx == 0);
    const bool xr = (bx == gridDim.x - 1);

    // phase-3 thread map (fixed across chunks)
    const int r3 = tid >> 4;          // 0..15 : row in chunk
    const int s3 = (tid >> 1) & 7;    // 0..7  : 4-col strip
    const int h3 = tid & 1;           // 0..1  : which 2-col half

    float part = 0.f;

    for (int c = 0; c < 2; ++c) {
        if (c) __syncthreads();                   // vb free? raw free? see ordering note
        const int yb = y0 + 16 * c - HALO;

        // ---- phase 1: global -> LDS raw (float4, whole-f4 edge masking) ----
        #pragma unroll
        for (int a = 0; a < 3; ++a) {
            const float* __restrict__ sp = (a == 0) ? fI : (a == 1) ? aI : bI;
            #pragma unroll 2
            for (int idx = tid; idx < CHROWS * RF4; idx += 256) {
                int r  = idx / RF4;               // const-divisor -> mul/shift
                int j4 = idx - r * RF4;
                int yy = yb + r;
                bool ok = ((unsigned)yy < (unsigned)H) &&
                          !(xl && j4 < 2) && !(xr && j4 >= 10);
                float4 v = make_float4(0.f, 0.f, 0.f, 0.f);
                if (ok)
                    v = *(const float4*)(sp + pbase + (size_t)yy * W +
                                         (x0 - XPAD + 4 * j4));
                *(float4*)(&raw[a][r * RSTR + 4 * j4]) = v;
            }
        }
        __syncthreads();

        // ---- phase 2: vertical blur of 8 fields into vb (16 rows) ----
        // task = (col j 0..41, row-pair rg 0..7) : 336 tasks
        for (int idx = tid; idx < NCOLS * 8; idx += 256) {
            int j  = idx % NCOLS;
            int rg = idx / NCOLS;
            float acc0[8], acc1[8];
            #pragma unroll
            for (int q = 0; q < 8; ++q) { acc0[q] = 0.f; acc1[q] = 0.f; }
            #pragma unroll
            for (int k = 0; k < 12; ++k) {
                int i = 2 * rg + k;
                float a0 = raw[0][i * RSTR + XPAD - HALO + j];
                float a1 = raw[1][i * RSTR + XPAD - HALO + j];
                float a2 = raw[2][i * RSTR + XPAD - HALO + j];
                float p[8];
                p[0] = a0; p[1] = a1; p[2] = a2;
                p[3] = a0 * a0; p[4] = a1 * a1; p[5] = a2 * a2;
                p[6] = a0 * a1; p[7] = a0 * a2;
                if (k <= 10) {
                    float w = gw.g[k];
                    #pragma unroll
                    for (int q = 0; q < 8; ++q) acc0[q] = fmaf(w, p[q], acc0[q]);
                }
                if (k >= 1) {
                    float w = gw.g[k - 1];
                    #pragma unroll
                    for (int q = 0; q < 8; ++q) acc1[q] = fmaf(w, p[q], acc1[q]);
                }
            }
            int R = 2 * rg;
            #pragma unroll
            for (int q = 0; q < 8; ++q) {
                vb[q][R * VSTR + j]       = acc0[q];
                vb[q][(R + 1) * VSTR + j] = acc1[q];
            }
        }
        __syncthreads();

        // ---- phase 3: horizontal blur (b128 LDS reads, pair-broadcast) + SSIM ----
        // thread (r3, s3, h3): out cols 4*s3 + 2*h3 + {0,1}, row r3
        float res[8][2];
        #pragma unroll
        for (int q = 0; q < 8; ++q) {
            const float4* vp = (const float4*)(&vb[q][r3 * VSTR + 4 * s3]);
            float4 w0 = vp[0], w1 = vp[1], w2 = vp[2], w3 = vp[3];
            float vr[16] = { w0.x, w0.y, w0.z, w0.w,  w1.x, w1.y, w1.z, w1.w,
                             w2.x, w2.y, w2.z, w2.w,  w3.x, w3.y, w3.z, w3.w };
            #pragma unroll
            for (int jj = 0; jj < 2; ++jj) {
                float acc = 0.f;
                #pragma unroll
                for (int t = 0; t < 11; ++t)
                    acc = fmaf(gw.g[t], vr[2 * h3 + jj + t], acc);
                res[q][jj] = acc;
            }
        }
        #pragma unroll
        for (int jj = 0; jj < 2; ++jj) {
            // fields: 0=F 1=A 2=B 3=F2 4=A2 5=B2 6=FA 7=FB
            part += ssim_term(res[0][jj], res[1][jj], res[3][jj], res[4][jj], res[6][jj]);
            part += ssim_term(res[0][jj], res[2][jj], res[3][jj], res[5][jj], res[7][jj]);
        }
        // ordering: next iter's phase-1 writes raw (phase-2 of this chunk done
        // before the sync above); next phase-2 writes vb only after the
        // post-stage sync, by which time this phase-3 has completed.
    }

    // ---- phase 4: block reduction -> one atomic ----
    #pragma unroll
    for (int off = 32; off > 0; off >>= 1) part += __shfl_down(part, off);
    if ((tid & 63) == 0) red[tid >> 6] = part;
    __syncthreads();
    if (tid == 0) atomicAdd(gsum, red[0] + red[1] + red[2] + red[3]);
}

__global__ void ssim_final(const float* __restrict__ gsum,
                           float* __restrict__ out, float invTwoN)
{
    out[0] = 1.f - gsum[0] * invTwoN;
}

extern "C" void kernel_launch(void* const* d_in, const int* in_sizes, int n_in,
                              void* d_out, int out_size, void* d_ws, size_t ws_size,
                              hipStream_t stream)
{
    const float* f  = (const float*)d_in[0];
    const float* s1 = (const float*)d_in[1];
    const float* s2 = (const float*)d_in[2];
    float* out  = (float*)d_out;
    float* gsum = (float*)d_ws;

    const int W = WIDTH, H = HEIGHT;
    const int N = in_sizes[0];          // 48 * 512 * 512
    const int planes = N / (W * H);

    GW gw;
    double gd[11], gs = 0.0;
    for (int i = 0; i < 11; ++i) {
        double d = (double)(i - 5);
        gd[i] = exp(-(d * d) / 4.5);    // 2*sigma^2 = 4.5
        gs += gd[i];
    }
    for (int i = 0; i < 11; ++i) gw.g[i] = (float)(gd[i] / gs);

    hipMemsetAsync(d_ws, 0, sizeof(float), stream);
    dim3 grid(W / TSX, H / 32, planes);
    ssim_tile<<<grid, dim3(256), 0, stream>>>(f, s1, s2, gsum, gw, W, H);
    ssim_final<<<1, 1, 0, stream>>>(gsum, out, 0.5f / (float)N);
}

// Round 3
// 297.720 us; speedup vs baseline: 2.9561x; 2.9561x over previous
//
#include <hip/hip_runtime.h>
#include <cmath>

#define TSX 32
#define HALO 5
#define XPAD 8        // staged halo per side (multiple of 4 for float4 masking)
#define NCOLS 42      // TSX + 2*HALO (columns vertical-blurred)
#define CHROWS 26     // 16 + 2*HALO  (input rows per 16-row chunk)
#define RSTR 48       // raw row stride (floats) = TSX + 2*XPAD
#define RF4 12        // float4s per raw row
#define VSTR 44       // vb row stride (floats), even for b64 alignment
#define WIDTH 512
#define HEIGHT 512

struct GW { float g[11]; };

__device__ __forceinline__ float ssim_term(float mu1, float mu2,
                                           float x2b, float y2b, float xyb)
{
    const float C1 = 1e-4f, C2 = 9e-4f;
    float mu12 = mu1 * mu2;
    float num  = (2.f * mu12 + C1) * (2.f * (xyb - mu12) + C2);
    float den  = (mu1 * mu1 + mu2 * mu2 + C1) *
                 ((x2b - mu1 * mu1) + (y2b - mu2 * mu2) + C2);
    return num / den;
}

__global__ __launch_bounds__(256, 4)
void ssim_tile(const float* __restrict__ fI, const float* __restrict__ aI,
               const float* __restrict__ bI, float* __restrict__ gsum,
               GW gw, int W, int H)
{
    __shared__ __align__(16) float raw[3][CHROWS * RSTR];   // 15.0 KB
    __shared__ __align__(16) float vb[8][16 * VSTR];        // 22.0 KB
    __shared__ float red[4];

    const int tid = threadIdx.x;
    const int bx = blockIdx.x;
    const int x0 = bx * TSX;
    const int y0 = blockIdx.y * 32;
    const size_t pbase = (size_t)blockIdx.z * (size_t)(W * H);
    const bool xl = (bx == 0);
    const bool xr = (bx == gridDim.x - 1);

    // phase-3 thread map: 16 rows x 16 two-col strips  (ALL indices static)
    const int r3 = tid >> 4;          // 0..15 : row in chunk
    const int s3 = tid & 15;          // 0..15 : 2-col strip

    // phase-2 thread map: 42 cols x 4 row-quads = 168 tasks (single pass)
    const int j2  = tid % NCOLS;      // 0..41
    const int rg2 = tid / NCOLS;      // 0..6 ; active iff rg2 < 4
    const bool p2act = (rg2 < 4);

    float part = 0.f;

    for (int c = 0; c < 2; ++c) {
        if (c) __syncthreads();           // vb of chunk0 consumed before reuse
        const int yb = y0 + 16 * c - HALO;

        // ---- phase 1: global -> LDS raw (float4, whole-f4 edge masking) ----
        #pragma unroll
        for (int a = 0; a < 3; ++a) {
            const float* __restrict__ sp = (a == 0) ? fI : (a == 1) ? aI : bI;
            #pragma unroll 2
            for (int idx = tid; idx < CHROWS * RF4; idx += 256) {
                int r  = idx / RF4;
                int j4 = idx - r * RF4;
                int yy = yb + r;
                bool ok = ((unsigned)yy < (unsigned)H) &&
                          !(xl && j4 < 2) && !(xr && j4 >= 10);
                float4 v = make_float4(0.f, 0.f, 0.f, 0.f);
                if (ok)
                    v = *(const float4*)(sp + pbase + (size_t)yy * W +
                                         (x0 - XPAD + 4 * j4));
                *(float4*)(&raw[a][r * RSTR + 4 * j4]) = v;
            }
        }
        __syncthreads();

        // ---- phase 2: vertical blur of 8 fields into vb (16 rows) ----
        // task = (col j2, row-quad rg2): 4 output rows per task, k = 0..14
        if (p2act) {
            float acc[4][8];
            #pragma unroll
            for (int ri = 0; ri < 4; ++ri)
                #pragma unroll
                for (int q = 0; q < 8; ++q) acc[ri][q] = 0.f;
            #pragma unroll
            for (int k = 0; k < 15; ++k) {
                int i = 4 * rg2 + k;
                float a0 = raw[0][i * RSTR + XPAD - HALO + j2];
                float a1 = raw[1][i * RSTR + XPAD - HALO + j2];
                float a2 = raw[2][i * RSTR + XPAD - HALO + j2];
                float p[8];
                p[0] = a0; p[1] = a1; p[2] = a2;
                p[3] = a0 * a0; p[4] = a1 * a1; p[5] = a2 * a2;
                p[6] = a0 * a1; p[7] = a0 * a2;
                #pragma unroll
                for (int ri = 0; ri < 4; ++ri) {
                    if (k >= ri && k - ri <= 10) {
                        float w = gw.g[k - ri];
                        #pragma unroll
                        for (int q = 0; q < 8; ++q)
                            acc[ri][q] = fmaf(w, p[q], acc[ri][q]);
                    }
                }
            }
            #pragma unroll
            for (int ri = 0; ri < 4; ++ri) {
                int R = 4 * rg2 + ri;
                #pragma unroll
                for (int q = 0; q < 8; ++q)
                    vb[q][R * VSTR + j2] = acc[ri][q];
            }
        }
        __syncthreads();

        // ---- phase 3: horizontal blur (aligned b64 reads, static idx) + SSIM --
        float res[8][2];
        #pragma unroll
        for (int q = 0; q < 8; ++q) {
            const float2* vp = (const float2*)(&vb[q][r3 * VSTR + 2 * s3]);
            float vr[14];
            #pragma unroll
            for (int t2 = 0; t2 < 7; ++t2) {
                float2 w = vp[t2];
                vr[2 * t2]     = w.x;
                vr[2 * t2 + 1] = w.y;
            }
            #pragma unroll
            for (int jj = 0; jj < 2; ++jj) {
                float acc = 0.f;
                #pragma unroll
                for (int t = 0; t < 11; ++t)
                    acc = fmaf(gw.g[t], vr[jj + t], acc);
                res[q][jj] = acc;
            }
        }
        #pragma unroll
        for (int jj = 0; jj < 2; ++jj) {
            // fields: 0=F 1=A 2=B 3=F2 4=A2 5=B2 6=FA 7=FB
            part += ssim_term(res[0][jj], res[1][jj], res[3][jj], res[4][jj], res[6][jj]);
            part += ssim_term(res[0][jj], res[2][jj], res[3][jj], res[5][jj], res[7][jj]);
        }
    }

    // ---- phase 4: block reduction -> one atomic ----
    #pragma unroll
    for (int off = 32; off > 0; off >>= 1) part += __shfl_down(part, off);
    if ((tid & 63) == 0) red[tid >> 6] = part;
    __syncthreads();
    if (tid == 0) atomicAdd(gsum, red[0] + red[1] + red[2] + red[3]);
}

__global__ void ssim_final(const float* __restrict__ gsum,
                           float* __restrict__ out, float invTwoN)
{
    out[0] = 1.f - gsum[0] * invTwoN;
}

extern "C" void kernel_launch(void* const* d_in, const int* in_sizes, int n_in,
                              void* d_out, int out_size, void* d_ws, size_t ws_size,
                              hipStream_t stream)
{
    const float* f  = (const float*)d_in[0];
    const float* s1 = (const float*)d_in[1];
    const float* s2 = (const float*)d_in[2];
    float* out  = (float*)d_out;
    float* gsum = (float*)d_ws;

    const int W = WIDTH, H = HEIGHT;
    const int N = in_sizes[0];          // 48 * 512 * 512
    const int planes = N / (W * H);

    GW gw;
    double gd[11], gs = 0.0;
    for (int i = 0; i < 11; ++i) {
        double d = (double)(i - 5);
        gd[i] = exp(-(d * d) / 4.5);    // 2*sigma^2 = 4.5
        gs += gd[i];
    }
    for (int i = 0; i < 11; ++i) gw.g[i] = (float)(gd[i] / gs);

    hipMemsetAsync(d_ws, 0, sizeof(float), stream);
    dim3 grid(W / TSX, H / 32, planes);
    ssim_tile<<<grid, dim3(256), 0, stream>>>(f, s1, s2, gsum, gw, W, H);
    ssim_final<<<1, 1, 0, stream>>>(gsum, out, 0.5f / (float)N);
}